// Round 12
// baseline (842.238 us; speedup 1.0000x reference)
//
#include <hip/hip_runtime.h>
#include <hip/hip_bf16.h>
#include <cstdint>

#define DI __device__ __forceinline__

using bf16x8 = __attribute__((ext_vector_type(8))) short;
using f32x4  = __attribute__((ext_vector_type(4))) float;

constexpr int IN_DIM = 384;
constexpr int HID    = 512;
constexpr int KTOT   = IN_DIM * 20;          // 7680: k = i*20 + t
constexpr int BM = 256, BN = 256, BK = 160;  // 8 input dims per K-step
constexpr int NSTEP = KTOT / BK;             // 48
// 8 waves (512 thr), wave grid 2(M) x 4(N), wave tile 128x64, acc[8][4].
// A: row stride 320B (=K bytes exactly) + bijective XOR swizzle addr^=(row&7)<<4 applied to
//    the FULL linear address on both write and read (R9-verified): 16-lane read phases hit
//    all 8 16B slots -> conflict-free. Scatter-write form (R7-proven faster than packed).
// B: K-plane transposed (plane p stride 4096B), DMA chunk-linear (R3 rule); b128 reads are
//    per-16-lane-phase 256B contiguous -> conflict-free (R7-proven at stride 2048).
constexpr int A_STRIDE_B = 320;
constexpr int A_BYTES    = BM * A_STRIDE_B;        // 81920
constexpr int B_BYTES    = 20 * BN * 16;           // 81920
constexpr int LDS_BYTES  = A_BYTES + B_BYTES;      // 163840 = 160 KiB exactly, 1 block/CU

DI unsigned short f2bf(float f) {
  union { float f; uint32_t u; } v; v.f = f;
  uint32_t r = (v.u + 0x7FFFu + ((v.u >> 16) & 1u)) >> 16;
  return (unsigned short)r;
}
DI float fast_tanh(float x) {
  float e = __expf(2.0f * x);
  return 1.0f - 2.0f / (e + 1.0f);
}
DI uint32_t swzw(uint32_t L) { return L ^ ((L >> 6) & 0x70u); }

#define GLOAD_LDS16(g, l)                                                        \
  __builtin_amdgcn_global_load_lds((const __attribute__((address_space(1))) void*)(g), \
                                   (__attribute__((address_space(3))) void*)(l), 16, 0, 0)

// ---------------- pack base_weight + spline_weight -> bf16 W[o][k], k = i*20 + t ----------------
__global__ __launch_bounds__(256) void kpack(const float* __restrict__ bw,
                                             const float* __restrict__ sw,
                                             unsigned short* __restrict__ Wb) {
  int idx = blockIdx.x * 256 + threadIdx.x;
  const float* s = sw + (size_t)idx * 19;
  unsigned short* d = Wb + (size_t)idx * 20;
  d[0] = f2bf(bw[idx]);
#pragma unroll
  for (int c = 0; c < 19; ++c) d[1 + c] = f2bf(s[c]);
}

// ---------------- fused KAN GEMM: h = tanh(A(x) @ W^T), 8 waves, wave tile 128x64 ----------------
__global__ __launch_bounds__(512, 1) void kgemm1(const float* __restrict__ z,
                                                 const float* __restrict__ ms,
                                                 const float* __restrict__ md,
                                                 const unsigned short* __restrict__ Wb,
                                                 unsigned short* __restrict__ hout) {
  extern __shared__ char ldsbuf[];
  char* AsB = ldsbuf;                         // 256 rows x 320B, XOR-swizzled
  char* BsB = ldsbuf + A_BYTES;               // 20 planes x 256 rows x 16B

  const int tid  = threadIdx.x;
  const int lane = tid & 63;
  const int wv   = tid >> 6;                  // 0..7
  const int wr   = wv >> 2;                   // 0..1 : M strip (128 rows)
  const int wc   = wv & 3;                    // 0..3 : N strip (64 cols)
  const int l16  = lane & 15;
  const int lhi  = lane >> 4;

  // XCD-aware bijective swizzle: grid 256 = 8 XCD * 32 (1 block/CU, single round)
  int wg = blockIdx.x;
  int id = (wg & 7) * 32 + (wg >> 3);
  const int mblk = id & 127;
  const int nblk = id >> 7;
  const int row0 = mblk * BM;
  const int col0 = nblk * BN;

  // B DMA precompute: chunk cl = rr*512 + tid -> row o = cl & 255, plane p = cl >> 8
  const unsigned short* gW0 = Wb + (size_t)(col0 + (tid & 255)) * KTOT + (tid >> 8) * 8;
  const uint32_t dma_l = (uint32_t)tid * 16u;

  // A-gen: isl constant per thread; 4 rows (arow0 + r*64) per thread
  const int isl = tid & 7;
  const int arow0 = tid >> 3;                 // 0..63
  const uint32_t fw = ((uint32_t)arow0 & 7u) << 4;   // row&7 invariant (+64 steps)

  // fragment read bases
  const uint32_t fA = (uint32_t)(l16 & 7) << 4;      // row&7 = l16&7 (wr*128, mi*16 multiples of 8)
  const uint32_t rA = (uint32_t)(wr * 128 + l16) * A_STRIDE_B + (uint32_t)lhi * 16u;
  const uint32_t rB = (uint32_t)(wc * 64 + l16) * 16u + (uint32_t)lhi * 4096u;

  f32x4 acc[8][4] = {};

  // x prefetch registers (s = 0 -> i = isl < 128 -> z)
  float xv0, xv1, xv2, xv3;
  {
    const float* xcol = z + isl;
    xv0 = xcol[(size_t)(row0 + arow0) * 128];
    xv1 = xcol[(size_t)(row0 + arow0 + 64) * 128];
    xv2 = xcol[(size_t)(row0 + arow0 + 128) * 128];
    xv3 = xcol[(size_t)(row0 + arow0 + 192) * 128];
  }

  for (int s = 0; s < NSTEP; ++s) {
    // ---- stage B: 10 chunks/thread (5120 chunks), K-plane layout, linear LDS dest
    const unsigned short* g = gW0 + s * BK;
#pragma unroll
    for (int rr = 0; rr < 10; ++rr)
      GLOAD_LDS16(g + rr * 16, BsB + dma_l + rr * 8192u);

    // ---- stage A: 4 tasks/thread; R7-proven scatter (zero 5xb64 + <=5 scalar), XOR-swizzled
#pragma unroll
    for (int r = 0; r < 4; ++r) {
      float x = (r == 0) ? xv0 : (r == 1) ? xv1 : (r == 2) ? xv2 : xv3;
      int arow = arow0 + r * 64;
      float xt = fast_tanh(x);
      float tt = (xt + 1.0f) * 8.0f;          // in [0,16]
      int   m  = (int)tt; m = m > 16 ? 16 : m;
      float u  = tt - (float)m;
      float omu = 1.0f - u;
      float u2 = u * u, u3 = u2 * u;
      float w0 = omu * omu * omu * (1.0f / 6.0f);
      float w1 = (3.0f * u3 - 6.0f * u2 + 4.0f) * (1.0f / 6.0f);
      float w2 = (-3.0f * u3 + 3.0f * u2 + 3.0f * u + 1.0f) * (1.0f / 6.0f);
      float w3 = u3 * (1.0f / 6.0f);
      float sil = xt / (1.0f + __expf(-xt));
      uint32_t base = (uint32_t)arow * A_STRIDE_B + (uint32_t)isl * 40u;
#pragma unroll
      for (int zz = 0; zz < 5; ++zz)
        *(uint64_t*)(AsB + ((base + zz * 8) ^ fw)) = 0ull;
      *(short*)(AsB + (base ^ fw)) = (short)f2bf(sil);                 // t = 0
      *(short*)(AsB + ((base + 2u * (m + 1)) ^ fw)) = (short)f2bf(w0); // c = m
      *(short*)(AsB + ((base + 2u * (m + 2)) ^ fw)) = (short)f2bf(w1);
      *(short*)(AsB + ((base + 2u * (m + 3)) ^ fw)) = (short)f2bf(w2);
      if (m < 16)                                                       // c = m+3 (drop c==19)
        *(short*)(AsB + ((base + 2u * (m + 4)) ^ fw)) = (short)f2bf(w3);
    }

    // ---- prefetch x for step s+1
    float xn0 = 0.f, xn1 = 0.f, xn2 = 0.f, xn3 = 0.f;
    if (s + 1 < NSTEP) {
      int i = (s + 1) * 8 + isl;
      const float* src = (i < 128) ? z : (i < 256 ? ms : md);
      const float* xcol = src + (i & 127);
      xn0 = xcol[(size_t)(row0 + arow0) * 128];
      xn1 = xcol[(size_t)(row0 + arow0 + 64) * 128];
      xn2 = xcol[(size_t)(row0 + arow0 + 128) * 128];
      xn3 = xcol[(size_t)(row0 + arow0 + 192) * 128];
    }

    __syncthreads();                          // drains vmcnt (DMA + x) + lgkm (A writes)
    // ---- compute: 5 K-sub-steps of 32; wave tile 128x64
#pragma unroll
    for (int ks = 0; ks < 5; ++ks) {
      bf16x8 af[8], bfr[4];
#pragma unroll
      for (int mi = 0; mi < 8; ++mi)
        af[mi] = *(const bf16x8*)(AsB + ((rA + (uint32_t)(mi * 16) * A_STRIDE_B + ks * 64u) ^ fA));
#pragma unroll
      for (int ni = 0; ni < 4; ++ni)
        bfr[ni] = *(const bf16x8*)(BsB + rB + (uint32_t)ks * 16384u + (uint32_t)ni * 256u);
#pragma unroll
      for (int mi = 0; mi < 8; ++mi)
#pragma unroll
        for (int ni = 0; ni < 4; ++ni)
          acc[mi][ni] = __builtin_amdgcn_mfma_f32_16x16x32_bf16(af[mi], bfr[ni], acc[mi][ni], 0, 0, 0);
    }
    __syncthreads();                          // protect LDS from next stage overwrite

    xv0 = xn0; xv1 = xn1; xv2 = xn2; xv3 = xn3;
  }

  // ---- epilogue: tanh -> bf16 h
#pragma unroll
  for (int mi = 0; mi < 8; ++mi)
#pragma unroll
    for (int ni = 0; ni < 4; ++ni)
#pragma unroll
      for (int rg = 0; rg < 4; ++rg) {
        int grow = row0 + wr * 128 + mi * 16 + lhi * 4 + rg;
        int gcol = col0 + wc * 64 + ni * 16 + l16;
        hout[(size_t)grow * HID + gcol] = f2bf(fast_tanh(acc[mi][ni][rg]));
      }
}

// ---------------- kfinal (MFMA): 64 rows/block, all 64 output cols ----------------
__global__ __launch_bounds__(256) void kfinal(const unsigned short* __restrict__ h,
                                              const float* __restrict__ lw,
                                              const float* __restrict__ lb,
                                              float* __restrict__ out) {
  __shared__ unsigned short Ws[64 * 512];
  char* WsB = (char*)Ws;
  const int tid  = threadIdx.x;
  const int lane = tid & 63;
  const int wv   = tid >> 6;
  const int l16  = lane & 15;
  const int lhi  = lane >> 4;
  const int row0 = blockIdx.x * 64;

#pragma unroll
  for (int it = 0; it < 16; ++it) {
    int c = it * 256 + tid;
    int r = c >> 6;
    int k8 = (c & 63) * 8;
    const float* g = lw + r * 512 + k8;
    float4 f0 = *(const float4*)g;
    float4 f1 = *(const float4*)(g + 4);
    union { unsigned short s[8]; bf16x8 v; } u;
    u.s[0] = f2bf(f0.x); u.s[1] = f2bf(f0.y); u.s[2] = f2bf(f0.z); u.s[3] = f2bf(f0.w);
    u.s[4] = f2bf(f1.x); u.s[5] = f2bf(f1.y); u.s[6] = f2bf(f1.z); u.s[7] = f2bf(f1.w);
    *(bf16x8*)(WsB + swzw((uint32_t)r * 1024u + (uint32_t)k8 * 2u)) = u.v;
  }
  __syncthreads();

  const int arow = row0 + wv * 16 + l16;
  const unsigned short* ag = h + (size_t)arow * HID + lhi * 8;
  f32x4 acc[4] = {};
#pragma unroll
  for (int ks = 0; ks < 16; ++ks) {
    bf16x8 af = *(const bf16x8*)(ag + ks * 32);
#pragma unroll
    for (int ni = 0; ni < 4; ++ni) {
      uint32_t L = (uint32_t)(ni * 16 + l16) * 1024u + (uint32_t)(ks * 64 + lhi * 16);
      bf16x8 bfr = *(const bf16x8*)(WsB + swzw(L));
      acc[ni] = __builtin_amdgcn_mfma_f32_16x16x32_bf16(af, bfr, acc[ni], 0, 0, 0);
    }
  }
#pragma unroll
  for (int ni = 0; ni < 4; ++ni) {
    int col = ni * 16 + l16;
    float bias = lb[col];
#pragma unroll
    for (int rg = 0; rg < 4; ++rg) {
      int grow = row0 + wv * 16 + lhi * 4 + rg;
      out[(size_t)grow * 64 + col] = acc[ni][rg] + bias;
    }
  }
}

extern "C" void kernel_launch(void* const* d_in, const int* in_sizes, int n_in,
                              void* d_out, int out_size, void* d_ws, size_t ws_size,
                              hipStream_t stream) {
  const float* z  = (const float*)d_in[0];
  const float* ms = (const float*)d_in[1];
  const float* md = (const float*)d_in[2];
  const float* bw = (const float*)d_in[3];
  const float* sw = (const float*)d_in[4];
  const float* lw = (const float*)d_in[5];
  const float* lb = (const float*)d_in[6];
  float* out = (float*)d_out;

  unsigned short* Wb = (unsigned short*)d_ws;                        // 7.5 MiB bf16 W [512][7680]
  unsigned short* hb = (unsigned short*)((char*)d_ws + (8u << 20));  // 32 MiB bf16 h [32768][512]

  (void)hipFuncSetAttribute((const void*)kgemm1,
                            hipFuncAttributeMaxDynamicSharedMemorySize, LDS_BYTES);

  kpack<<<(HID * IN_DIM) / 256, 256, 0, stream>>>(bw, sw, Wb);
  kgemm1<<<256, 512, LDS_BYTES, stream>>>(z, ms, md, Wb, hb);
  kfinal<<<32768 / 64, 256, 0, stream>>>(hb, lw, lb, out);
}

// Round 13
// 357.456 us; speedup vs baseline: 2.3562x; 2.3562x over previous
//
#include <hip/hip_runtime.h>
#include <hip/hip_bf16.h>
#include <cstdint>

#define DI __device__ __forceinline__

using bf16x8 = __attribute__((ext_vector_type(8))) short;
using f32x4  = __attribute__((ext_vector_type(4))) float;

constexpr int IN_DIM = 384;
constexpr int HID    = 512;
constexpr int KTOT   = IN_DIM * 20;          // 7680: k = i*20 + t
constexpr int BM = 128, BN = 256, BK = 160;  // 8 input dims per K-step
constexpr int NSTEP = KTOT / BK;             // 48
// R5-champion layouts, tile aspect swapped to BN=256 (halves A-gen redundancy = HID/BN).
// A: row-major, 336B stride (mod 128 = 80) -> 16-lane b128 read phases cycle all 8 slots
//    (conflict-free, proven R4-R8); plain ds_write, contiguous 40B per task.
// B: row-major 320B, DMA chunk-linear (R3 rule: wave-uniform base + lane*16, no predication).
constexpr int A_STRIDE_B = 336;
constexpr int B_STRIDE_B = 320;
constexpr int A_BYTES    = BM * A_STRIDE_B;        // 43008
constexpr int B_BYTES    = BN * B_STRIDE_B;        // 81920
constexpr int LDS_BYTES  = A_BYTES + B_BYTES;      // 124928 -> 1 block/CU

DI unsigned short f2bf(float f) {
  union { float f; uint32_t u; } v; v.f = f;
  uint32_t r = (v.u + 0x7FFFu + ((v.u >> 16) & 1u)) >> 16;
  return (unsigned short)r;
}
DI float fast_tanh(float x) {
  float e = __expf(2.0f * x);
  return 1.0f - 2.0f / (e + 1.0f);
}
DI uint32_t swzw(uint32_t L) { return L ^ ((L >> 6) & 0x70u); }

#define GLOAD_LDS16(g, l)                                                        \
  __builtin_amdgcn_global_load_lds((const __attribute__((address_space(1))) void*)(g), \
                                   (__attribute__((address_space(3))) void*)(l), 16, 0, 0)

// ---------------- pack base_weight + spline_weight -> bf16 W[o][k], k = i*20 + t ----------------
__global__ __launch_bounds__(256) void kpack(const float* __restrict__ bw,
                                             const float* __restrict__ sw,
                                             unsigned short* __restrict__ Wb) {
  int idx = blockIdx.x * 256 + threadIdx.x;
  const float* s = sw + (size_t)idx * 19;
  unsigned short* d = Wb + (size_t)idx * 20;
  d[0] = f2bf(bw[idx]);
#pragma unroll
  for (int c = 0; c < 19; ++c) d[1 + c] = f2bf(s[c]);
}

// ---------------- fused KAN GEMM: h = tanh(A(x) @ W^T), 8 waves, wave tile 64x64 ----------------
__global__ __launch_bounds__(512, 2) void kgemm1(const float* __restrict__ z,
                                                 const float* __restrict__ ms,
                                                 const float* __restrict__ md,
                                                 const unsigned short* __restrict__ Wb,
                                                 unsigned short* __restrict__ hout) {
  extern __shared__ char ldsbuf[];
  char* AsB = ldsbuf;                         // 128 rows x 336B
  char* BsB = ldsbuf + A_BYTES;               // 256 rows x 320B

  const int tid  = threadIdx.x;
  const int lane = tid & 63;
  const int wv   = tid >> 6;                  // 0..7
  const int wr   = wv >> 2;                   // 0..1 : M strip (64 rows)
  const int wc   = wv & 3;                    // 0..3 : N strip (64 cols)
  const int l16  = lane & 15;
  const int lhi  = lane >> 4;

  // XCD-aware bijective swizzle: grid 512 = 8 XCD * 64
  int wg = blockIdx.x;
  int id = (wg & 7) * 64 + (wg >> 3);
  const int mblk = id & 255;                  // 256 M-blocks
  const int nblk = id >> 8;                   // 2 N-blocks
  const int row0 = mblk * BM;
  const int col0 = nblk * BN;

  // B DMA: 10 chunks/thread; per-rr global offsets precomputed (static unroll -> registers)
  uint32_t boff[10];
#pragma unroll
  for (int rr = 0; rr < 10; ++rr) {
    int cl = rr * 512 + tid;
    int o  = cl / 20;
    int sl = cl - o * 20;
    boff[rr] = (uint32_t)(col0 + o) * (uint32_t)KTOT + (uint32_t)sl * 8u;
  }
  const uint32_t dma_l = (uint32_t)tid * 16u; // dst chunk*16 = tid*16 + rr*8192

  // A-gen: isl constant per thread; 2 rows (arow0, arow0+64) per thread
  const int isl = tid & 7;
  const int arow0 = tid >> 3;                 // 0..63

  // fragment read bases
  const uint32_t rA = (uint32_t)(wr * 64 + l16) * A_STRIDE_B + (uint32_t)lhi * 16u;
  const uint32_t rB = (uint32_t)(wc * 64 + l16) * B_STRIDE_B + (uint32_t)lhi * 16u;

  f32x4 acc[4][4] = {};

  // x prefetch registers (s=0 -> i = isl < 128 -> z)
  float xv0, xv1;
  {
    const float* xcol = z + isl;
    xv0 = xcol[(size_t)(row0 + arow0) * 128];
    xv1 = xcol[(size_t)(row0 + arow0 + 64) * 128];
  }

  for (int s = 0; s < NSTEP; ++s) {
    // ---- stage B: 10 chunks/thread, row-major 320B, linear LDS dest, full waves active
    const uint32_t soff = (uint32_t)s * BK;
#pragma unroll
    for (int rr = 0; rr < 10; ++rr)
      GLOAD_LDS16(Wb + boff[rr] + soff, BsB + dma_l + rr * 8192u);

    // ---- stage A: 2 tasks/thread; R5-proven scatter (zero 5xb64 + <=5 scalar b16)
#pragma unroll
    for (int r = 0; r < 2; ++r) {
      float x = (r == 0) ? xv0 : xv1;
      int arow = arow0 + r * 64;
      float xt = fast_tanh(x);
      float tt = (xt + 1.0f) * 8.0f;          // in [0,16]
      int   m  = (int)tt; m = m > 16 ? 16 : m;
      float u  = tt - (float)m;
      float omu = 1.0f - u;
      float u2 = u * u, u3 = u2 * u;
      float w0 = omu * omu * omu * (1.0f / 6.0f);
      float w1 = (3.0f * u3 - 6.0f * u2 + 4.0f) * (1.0f / 6.0f);
      float w2 = (-3.0f * u3 + 3.0f * u2 + 3.0f * u + 1.0f) * (1.0f / 6.0f);
      float w3 = u3 * (1.0f / 6.0f);
      float sil = xt / (1.0f + __expf(-xt));
      uint32_t base = (uint32_t)arow * A_STRIDE_B + (uint32_t)isl * 40u;
#pragma unroll
      for (int zz = 0; zz < 5; ++zz)
        *(uint64_t*)(AsB + base + zz * 8) = 0ull;
      *(short*)(AsB + base) = (short)f2bf(sil);                 // t = 0
      *(short*)(AsB + base + 2u * (m + 1)) = (short)f2bf(w0);   // c = m
      *(short*)(AsB + base + 2u * (m + 2)) = (short)f2bf(w1);
      *(short*)(AsB + base + 2u * (m + 3)) = (short)f2bf(w2);
      if (m < 16)                                                // c = m+3 (drop c==19)
        *(short*)(AsB + base + 2u * (m + 4)) = (short)f2bf(w3);
    }

    // ---- prefetch x for step s+1
    float xn0 = 0.f, xn1 = 0.f;
    if (s + 1 < NSTEP) {
      int i = (s + 1) * 8 + isl;
      const float* src = (i < 128) ? z : (i < 256 ? ms : md);
      const float* xcol = src + (i & 127);
      xn0 = xcol[(size_t)(row0 + arow0) * 128];
      xn1 = xcol[(size_t)(row0 + arow0 + 64) * 128];
    }

    __syncthreads();                          // drains vmcnt (DMA + x) + lgkm (A writes)
    // ---- compute: 5 K-sub-steps of 32; wave tile 64x64
#pragma unroll
    for (int ks = 0; ks < 5; ++ks) {
      bf16x8 af[4], bfr[4];
#pragma unroll
      for (int mi = 0; mi < 4; ++mi)
        af[mi] = *(const bf16x8*)(AsB + rA + (uint32_t)(mi * 16) * A_STRIDE_B + ks * 64u);
#pragma unroll
      for (int ni = 0; ni < 4; ++ni)
        bfr[ni] = *(const bf16x8*)(BsB + rB + (uint32_t)(ni * 16) * B_STRIDE_B + ks * 64u);
#pragma unroll
      for (int mi = 0; mi < 4; ++mi)
#pragma unroll
        for (int ni = 0; ni < 4; ++ni)
          acc[mi][ni] = __builtin_amdgcn_mfma_f32_16x16x32_bf16(af[mi], bfr[ni], acc[mi][ni], 0, 0, 0);
    }
    __syncthreads();                          // protect LDS from next stage overwrite

    xv0 = xn0; xv1 = xn1;
  }

  // ---- epilogue: tanh -> bf16 h
#pragma unroll
  for (int mi = 0; mi < 4; ++mi)
#pragma unroll
    for (int ni = 0; ni < 4; ++ni)
#pragma unroll
      for (int rg = 0; rg < 4; ++rg) {
        int grow = row0 + wr * 64 + mi * 16 + lhi * 4 + rg;
        int gcol = col0 + wc * 64 + ni * 16 + l16;
        hout[(size_t)grow * HID + gcol] = f2bf(fast_tanh(acc[mi][ni][rg]));
      }
}

// ---------------- kfinal (MFMA): 64 rows/block, all 64 output cols ----------------
__global__ __launch_bounds__(256) void kfinal(const unsigned short* __restrict__ h,
                                              const float* __restrict__ lw,
                                              const float* __restrict__ lb,
                                              float* __restrict__ out) {
  __shared__ unsigned short Ws[64 * 512];
  char* WsB = (char*)Ws;
  const int tid  = threadIdx.x;
  const int lane = tid & 63;
  const int wv   = tid >> 6;
  const int l16  = lane & 15;
  const int lhi  = lane >> 4;
  const int row0 = blockIdx.x * 64;

#pragma unroll
  for (int it = 0; it < 16; ++it) {
    int c = it * 256 + tid;
    int r = c >> 6;
    int k8 = (c & 63) * 8;
    const float* g = lw + r * 512 + k8;
    float4 f0 = *(const float4*)g;
    float4 f1 = *(const float4*)(g + 4);
    union { unsigned short s[8]; bf16x8 v; } u;
    u.s[0] = f2bf(f0.x); u.s[1] = f2bf(f0.y); u.s[2] = f2bf(f0.z); u.s[3] = f2bf(f0.w);
    u.s[4] = f2bf(f1.x); u.s[5] = f2bf(f1.y); u.s[6] = f2bf(f1.z); u.s[7] = f2bf(f1.w);
    *(bf16x8*)(WsB + swzw((uint32_t)r * 1024u + (uint32_t)k8 * 2u)) = u.v;
  }
  __syncthreads();

  const int arow = row0 + wv * 16 + l16;
  const unsigned short* ag = h + (size_t)arow * HID + lhi * 8;
  f32x4 acc[4] = {};
#pragma unroll
  for (int ks = 0; ks < 16; ++ks) {
    bf16x8 af = *(const bf16x8*)(ag + ks * 32);
#pragma unroll
    for (int ni = 0; ni < 4; ++ni) {
      uint32_t L = (uint32_t)(ni * 16 + l16) * 1024u + (uint32_t)(ks * 64 + lhi * 16);
      bf16x8 bfr = *(const bf16x8*)(WsB + swzw(L));
      acc[ni] = __builtin_amdgcn_mfma_f32_16x16x32_bf16(af, bfr, acc[ni], 0, 0, 0);
    }
  }
#pragma unroll
  for (int ni = 0; ni < 4; ++ni) {
    int col = ni * 16 + l16;
    float bias = lb[col];
#pragma unroll
    for (int rg = 0; rg < 4; ++rg) {
      int grow = row0 + wv * 16 + lhi * 4 + rg;
      out[(size_t)grow * 64 + col] = acc[ni][rg] + bias;
    }
  }
}

extern "C" void kernel_launch(void* const* d_in, const int* in_sizes, int n_in,
                              void* d_out, int out_size, void* d_ws, size_t ws_size,
                              hipStream_t stream) {
  const float* z  = (const float*)d_in[0];
  const float* ms = (const float*)d_in[1];
  const float* md = (const float*)d_in[2];
  const float* bw = (const float*)d_in[3];
  const float* sw = (const float*)d_in[4];
  const float* lw = (const float*)d_in[5];
  const float* lb = (const float*)d_in[6];
  float* out = (float*)d_out;

  unsigned short* Wb = (unsigned short*)d_ws;                        // 7.5 MiB bf16 W [512][7680]
  unsigned short* hb = (unsigned short*)((char*)d_ws + (8u << 20));  // 32 MiB bf16 h [32768][512]

  (void)hipFuncSetAttribute((const void*)kgemm1,
                            hipFuncAttributeMaxDynamicSharedMemorySize, LDS_BYTES);

  kpack<<<(HID * IN_DIM) / 256, 256, 0, stream>>>(bw, sw, Wb);
  kgemm1<<<512, 512, LDS_BYTES, stream>>>(z, ms, md, Wb, hb);
  kfinal<<<32768 / 64, 256, 0, stream>>>(hb, lw, lb, out);
}